// Round 3
// baseline (453.372 us; speedup 1.0000x reference)
//
#include <hip/hip_runtime.h>
#include <hip/hip_bf16.h>
#include <cstdint>

// ---------------------------------------------------------------------------
// WindowAttention, round 3: occupancy-first split.
//  prep:    weights -> bf16 [n][k]; comb = rel_bias + mask (fp32).
//  qkvattn: one block (256 thr) per (window, head). Per-head QKV GEMM
//           (B-frags global->reg, no inner barriers), attention (softmax in
//           regs), Xa slice -> global bf16. LDS 49.7 KB -> 3 blocks/CU.
//           Block swizzle keeps all 6 heads of a window on one XCD,
//           temporally adjacent -> X fetched from HBM once, L2-served 5x.
//  proj:    one block (256 thr) per window. Xa -> LDS, 1 barrier,
//           B-frags global->reg, fp32 out + bias. 16 waves/CU.
// ---------------------------------------------------------------------------

#define NTOK 64
#define NH 6
#define HD 32
#define WDIM 192
#define SCALE 0.17677669529663689f

typedef __bf16 bf16x8 __attribute__((ext_vector_type(8)));
typedef float f32x4 __attribute__((ext_vector_type(4)));

__device__ inline unsigned short f2bf(float f) {
    union { float f; unsigned u; } v; v.f = f;
    unsigned r = v.u + 0x7fff + ((v.u >> 16) & 1);   // RNE
    return (unsigned short)(r >> 16);
}

// ---------------------------------------------------------------------------
// K0: weight transpose/cast + combined bias table
// ---------------------------------------------------------------------------
__global__ __launch_bounds__(256) void prep_kernel(
    const float* __restrict__ w_qkv, const float* __restrict__ w_proj,
    const float* __restrict__ rpbt, const float* __restrict__ mask,
    unsigned short* __restrict__ wqkv_t, unsigned short* __restrict__ wproj_t,
    float* __restrict__ comb) {
    int idx = blockIdx.x * 256 + threadIdx.x;
    if (idx < 576 * 192) {
        int n = idx / 192, k = idx % 192;
        wqkv_t[idx] = f2bf(w_qkv[k * 576 + n]);
        return;
    }
    int i2 = idx - 576 * 192;
    if (i2 < 192 * 192) {
        int n = i2 / 192, k = i2 % 192;
        wproj_t[i2] = f2bf(w_proj[k * 192 + n]);
        return;
    }
    int i3 = i2 - 192 * 192;
    if (i3 < 64 * NH * NTOK * NTOK) {
        int c = i3 & 63, r = (i3 >> 6) & 63;
        int h = (i3 >> 12) % NH;
        int w = i3 / (NH * 4096);
        int rr = (r >> 3) - (c >> 3) + 7;
        int cc = (r & 7) - (c & 7) + 7;
        comb[i3] = rpbt[(rr * 15 + cc) * NH + h] + mask[w * 4096 + r * 64 + c];
    }
}

// LDS strides (shorts): chosen so b128 accesses land <=2-way per bank (free).
#define LXP 200   // X rows: 100 dwords = 4 mod 32
#define LQP 40    // q/k rows: 20 dwords = 20 mod 32
#define LVP 72    // v^T rows: 36 dwords = 4 mod 32
#define LPP 72    // P rows

// ---------------------------------------------------------------------------
// K1: per-(window, head) QKV + attention.
// blockIdx swizzle: idx = (w/8)*48 + h*8 + (w%8)  -> idx%8 == w%8 (XCD-stable)
// ---------------------------------------------------------------------------
__global__ __launch_bounds__(256, 3) void qkvattn_kernel(
    const float* __restrict__ X, const unsigned short* __restrict__ Wqkv,
    const float* __restrict__ b_qkv, const float* __restrict__ comb,
    unsigned short* __restrict__ Xa, int B) {
    __shared__ unsigned short lx[64 * LXP];      // 25.6 KB
    __shared__ unsigned short lq[64 * LQP];      //  5.1 KB
    __shared__ unsigned short lk[64 * LQP];      //  5.1 KB
    __shared__ unsigned short lvt[32 * LVP];     //  4.6 KB
    __shared__ unsigned short lp[4 * 16 * LPP];  //  9.2 KB  per-wave P

    const int idx = blockIdx.x;
    const int g = idx / 48, r48 = idx % 48;
    const int h = r48 >> 3;
    const int w = g * 8 + (r48 & 7);
    if (w >= B) return;                           // uniform per block

    const int tid = threadIdx.x;
    const int wave = tid >> 6, lane = tid & 63;
    const int l15 = lane & 15, quad = lane >> 4;

    // ---- stage X (fp32 -> bf16) ----
    const float4* xg = (const float4*)(X + (size_t)w * NTOK * WDIM);
    #pragma unroll
    for (int i = 0; i < 12; i++) {
        int e4 = tid + i * 256;                  // 3072 float4
        int row = e4 / 48, c4 = e4 % 48;
        float4 v = xg[e4];
        union { unsigned short s[4]; uint2 u; } pk;
        pk.s[0] = f2bf(v.x); pk.s[1] = f2bf(v.y);
        pk.s[2] = f2bf(v.z); pk.s[3] = f2bf(v.w);
        *(uint2*)&lx[row * LXP + c4 * 4] = pk.u;
    }
    __syncthreads();

    // ---- per-head QKV GEMM: M=64 (wave = m-tile), N=96 (6 n-tiles), K=192 ----
    // n-tile nt: part = nt>>1 (0=q,1=k,2=v), dcol = (nt&1)*16 + l15
    f32x4 acc[6];
    #pragma unroll
    for (int nt = 0; nt < 6; nt++) acc[nt] = (f32x4){0.f, 0.f, 0.f, 0.f};

    #pragma unroll
    for (int kh = 0; kh < 2; kh++) {             // two K-halves of 96
        bf16x8 bfr[6][3];
        #pragma unroll
        for (int nt = 0; nt < 6; nt++) {
            int wrow = (nt >> 1) * 192 + h * 32 + (nt & 1) * 16 + l15;
            #pragma unroll
            for (int k3 = 0; k3 < 3; k3++)
                bfr[nt][k3] = *(const bf16x8*)&Wqkv[
                    (size_t)wrow * 192 + (kh * 3 + k3) * 32 + quad * 8];
        }
        #pragma unroll
        for (int k3 = 0; k3 < 3; k3++) {
            bf16x8 af = *(const bf16x8*)&lx[
                (wave * 16 + l15) * LXP + (kh * 3 + k3) * 32 + quad * 8];
            #pragma unroll
            for (int nt = 0; nt < 6; nt++)
                acc[nt] = __builtin_amdgcn_mfma_f32_16x16x32_bf16(
                    af, bfr[nt][k3], acc[nt], 0, 0, 0);
        }
    }

    // epilogue: C/D layout col=l15, row=quad*4+r; SCALE folded into q
    #pragma unroll
    for (int nt = 0; nt < 6; nt++) {
        int part = nt >> 1, d = (nt & 1) * 16 + l15;
        float bias = b_qkv[part * 192 + h * 32 + d];
        #pragma unroll
        for (int r = 0; r < 4; r++) {
            int t = wave * 16 + quad * 4 + r;
            float v = acc[nt][r] + bias;
            if (part == 0)      lq[t * LQP + d] = f2bf(v * SCALE);
            else if (part == 1) lk[t * LQP + d] = f2bf(v);
            else                lvt[d * LVP + t] = f2bf(v);
        }
    }
    __syncthreads();

    // ---- attention: wave owns query rows [16*wave, 16*wave+16) ----
    const int mbase = wave * 16;
    const float* cb = comb + ((size_t)(w & 63) * NH + h) * 4096;
    unsigned short* pw = &lp[wave * 16 * LPP];

    bf16x8 aq = *(const bf16x8*)&lq[(mbase + l15) * LQP + quad * 8];
    f32x4 sacc[4];
    #pragma unroll
    for (int j = 0; j < 4; j++) {
        bf16x8 bk = *(const bf16x8*)&lk[(j * 16 + l15) * LQP + quad * 8];
        f32x4 z = (f32x4){0.f, 0.f, 0.f, 0.f};
        sacc[j] = __builtin_amdgcn_mfma_f32_16x16x32_bf16(aq, bk, z, 0, 0, 0);
    }

    // softmax fp32: row = mbase+quad*4+r lives in a 16-lane shfl group
    float s[4][4];
    #pragma unroll
    for (int j = 0; j < 4; j++)
        #pragma unroll
        for (int r = 0; r < 4; r++)
            s[j][r] = sacc[j][r] + cb[(mbase + quad * 4 + r) * 64 + j * 16 + l15];
    float p[4][4], rsum[4];
    #pragma unroll
    for (int r = 0; r < 4; r++) {
        float m = fmaxf(fmaxf(s[0][r], s[1][r]), fmaxf(s[2][r], s[3][r]));
        for (int o = 1; o < 16; o <<= 1) m = fmaxf(m, __shfl_xor(m, o, 64));
        #pragma unroll
        for (int j = 0; j < 4; j++) p[j][r] = __expf(s[j][r] - m);
        float su = p[0][r] + p[1][r] + p[2][r] + p[3][r];
        for (int o = 1; o < 16; o <<= 1) su += __shfl_xor(su, o, 64);
        rsum[r] = su;
    }
    // P -> per-wave LDS slice (same-wave RAW only)
    #pragma unroll
    for (int j = 0; j < 4; j++)
        #pragma unroll
        for (int r = 0; r < 4; r++)
            pw[(quad * 4 + r) * LPP + j * 16 + l15] = f2bf(p[j][r]);

    // O = P V
    f32x4 oacc[2];
    oacc[0] = (f32x4){0.f, 0.f, 0.f, 0.f};
    oacc[1] = (f32x4){0.f, 0.f, 0.f, 0.f};
    #pragma unroll
    for (int kstep = 0; kstep < 2; kstep++) {
        bf16x8 ap = *(const bf16x8*)&pw[l15 * LPP + kstep * 32 + quad * 8];
        #pragma unroll
        for (int n2 = 0; n2 < 2; n2++) {
            bf16x8 bv = *(const bf16x8*)&lvt[
                (n2 * 16 + l15) * LVP + kstep * 32 + quad * 8];
            oacc[n2] = __builtin_amdgcn_mfma_f32_16x16x32_bf16(ap, bv, oacc[n2], 0, 0, 0);
        }
    }
    // normalize + write Xa slice (bf16, [win][t][h*32+d])
    #pragma unroll
    for (int r = 0; r < 4; r++) {
        float inv = 1.0f / rsum[r];
        int t = mbase + quad * 4 + r;
        #pragma unroll
        for (int n2 = 0; n2 < 2; n2++)
            Xa[((size_t)w * NTOK + t) * WDIM + h * 32 + n2 * 16 + l15] =
                f2bf(oacc[n2][r] * inv);
    }
}

// ---------------------------------------------------------------------------
// K2: output projection, one block (256 thr) per window, 1 barrier.
// ---------------------------------------------------------------------------
__global__ __launch_bounds__(256, 4) void proj_kernel(
    const unsigned short* __restrict__ Xa, const unsigned short* __restrict__ Wt,
    const float* __restrict__ b_proj, float* __restrict__ out) {
    __shared__ unsigned short lx[64 * LXP];
    const int tid = threadIdx.x;
    const int bwin = blockIdx.x;

    const unsigned short* xg = Xa + (size_t)bwin * NTOK * WDIM;
    #pragma unroll
    for (int i = 0; i < 6; i++) {
        int e8 = tid + i * 256;                  // 1536 chunks of 8 bf16
        int row = e8 / 24, c8 = e8 % 24;
        *(uint4*)&lx[row * LXP + c8 * 8] = *(const uint4*)&xg[row * 192 + c8 * 8];
    }
    __syncthreads();

    const int wave = tid >> 6, lane = tid & 63;
    const int l15 = lane & 15, quad = lane >> 4;
    const int nbase = wave * 48;

    f32x4 acc[4][3];
    #pragma unroll
    for (int mt = 0; mt < 4; mt++)
        #pragma unroll
        for (int nt = 0; nt < 3; nt++)
            acc[mt][nt] = (f32x4){0.f, 0.f, 0.f, 0.f};

    #pragma unroll
    for (int kh = 0; kh < 2; kh++) {
        bf16x8 pfr[3][3];
        #pragma unroll
        for (int nt = 0; nt < 3; nt++)
            #pragma unroll
            for (int k3 = 0; k3 < 3; k3++)
                pfr[nt][k3] = *(const bf16x8*)&Wt[
                    (size_t)(nbase + nt * 16 + l15) * 192 + (kh * 3 + k3) * 32 + quad * 8];
        #pragma unroll
        for (int k3 = 0; k3 < 3; k3++) {
            bf16x8 af[4];
            #pragma unroll
            for (int mt = 0; mt < 4; mt++)
                af[mt] = *(const bf16x8*)&lx[
                    (mt * 16 + l15) * LXP + (kh * 3 + k3) * 32 + quad * 8];
            #pragma unroll
            for (int mt = 0; mt < 4; mt++)
                #pragma unroll
                for (int nt = 0; nt < 3; nt++)
                    acc[mt][nt] = __builtin_amdgcn_mfma_f32_16x16x32_bf16(
                        af[mt], pfr[nt][k3], acc[mt][nt], 0, 0, 0);
        }
    }

    #pragma unroll
    for (int nt = 0; nt < 3; nt++) {
        int cw = nbase + nt * 16 + l15;
        float bias = b_proj[cw];
        #pragma unroll
        for (int mt = 0; mt < 4; mt++)
            #pragma unroll
            for (int r = 0; r < 4; r++) {
                int t = mt * 16 + quad * 4 + r;
                out[((size_t)bwin * NTOK + t) * WDIM + cw] = acc[mt][nt][r] + bias;
            }
    }
}

// ---------------------------------------------------------------------------
extern "C" void kernel_launch(void* const* d_in, const int* in_sizes, int n_in,
                              void* d_out, int out_size, void* d_ws, size_t ws_size,
                              hipStream_t stream) {
    const float* x      = (const float*)d_in[0];
    const float* mask   = (const float*)d_in[1];
    const float* w_qkv  = (const float*)d_in[2];
    const float* b_qkv  = (const float*)d_in[3];
    const float* rpbt   = (const float*)d_in[4];
    const float* w_proj = (const float*)d_in[5];
    const float* b_proj = (const float*)d_in[6];
    float* out = (float*)d_out;

    const int B = in_sizes[0] / (NTOK * WDIM);   // 2048

    char* ws = (char*)d_ws;
    size_t o = 0;
    unsigned short* Wq = (unsigned short*)(ws + o); o += 576 * 192 * 2;
    unsigned short* Wp = (unsigned short*)(ws + o); o += 192 * 192 * 2;
    float* comb        = (float*)(ws + o);         o += (size_t)64 * NH * NTOK * NTOK * 4;
    unsigned short* Xa = (unsigned short*)(ws + o); o += (size_t)B * NTOK * WDIM * 2;

    const int prep_elems = 576 * 192 + 192 * 192 + 64 * NH * NTOK * NTOK;
    prep_kernel<<<(prep_elems + 255) / 256, 256, 0, stream>>>(
        w_qkv, w_proj, rpbt, mask, Wq, Wp, comb);
    qkvattn_kernel<<<((B + 7) / 8) * 48, 256, 0, stream>>>(
        x, Wq, b_qkv, comb, Xa, B);
    proj_kernel<<<B, 256, 0, stream>>>(Xa, Wp, b_proj, out);
}

// Round 4
// 358.690 us; speedup vs baseline: 1.2640x; 1.2640x over previous
//
#include <hip/hip_runtime.h>
#include <hip/hip_bf16.h>
#include <cstdint>

// ---------------------------------------------------------------------------
// WindowAttention, round 4: round-1 topology, barriers removed.
//  prep: weights -> bf16 [n][k]; comb = rel_bias + mask (fp32).
//  qkv:  one block per window. X staged once (fp32->bf16, 1 barrier),
//        3 chunks x (W B-frags global->reg, ZERO inner barriers).
//        Q written pre-scaled. ~250 MB traffic -> memory-bound.
//  attn: one block per (window,head). Q/K/V staged (V^T with rotated write
//        order to kill the 8-way bank conflict), comb read direct from L2/L3,
//        softmax fp32 in regs, Xa bf16 out.
//  proj: one block per window, W-in-regs, 1 barrier, fp32 out + bias.
// Model: dur_us ~ 120us harness overhead + sum(kernels).
// ---------------------------------------------------------------------------

#define NTOK 64
#define NH 6
#define HD 32
#define WDIM 192
#define SCALE 0.17677669529663689f

typedef __bf16 bf16x8 __attribute__((ext_vector_type(8)));
typedef float f32x4 __attribute__((ext_vector_type(4)));

__device__ inline unsigned short f2bf(float f) {
    union { float f; unsigned u; } v; v.f = f;
    unsigned r = v.u + 0x7fff + ((v.u >> 16) & 1);   // RNE
    return (unsigned short)(r >> 16);
}

// ---------------------------------------------------------------------------
// K0: weight transpose/cast + combined bias table
// ---------------------------------------------------------------------------
__global__ __launch_bounds__(256) void prep_kernel(
    const float* __restrict__ w_qkv, const float* __restrict__ w_proj,
    const float* __restrict__ rpbt, const float* __restrict__ mask,
    unsigned short* __restrict__ wqkv_t, unsigned short* __restrict__ wproj_t,
    float* __restrict__ comb) {
    int idx = blockIdx.x * 256 + threadIdx.x;
    if (idx < 576 * 192) {
        int n = idx / 192, k = idx % 192;
        wqkv_t[idx] = f2bf(w_qkv[k * 576 + n]);
        return;
    }
    int i2 = idx - 576 * 192;
    if (i2 < 192 * 192) {
        int n = i2 / 192, k = i2 % 192;
        wproj_t[i2] = f2bf(w_proj[k * 192 + n]);
        return;
    }
    int i3 = i2 - 192 * 192;
    if (i3 < 64 * NH * NTOK * NTOK) {
        int c = i3 & 63, r = (i3 >> 6) & 63;
        int h = (i3 >> 12) % NH;
        int w = i3 / (NH * 4096);
        int rr = (r >> 3) - (c >> 3) + 7;
        int cc = (r & 7) - (c & 7) + 7;
        comb[i3] = rpbt[(rr * 15 + cc) * NH + h] + mask[w * 4096 + r * 64 + c];
    }
}

#define LXP 200   // X rows (192 used)
#define LQP 40    // q/k rows (32 used)
#define LVP 72    // v^T rows (64 used)
#define LPP 72    // P rows (64 used)

// ---------------------------------------------------------------------------
// K1: QKV GEMM. Block = window (64x576x192). Wave covers n-slice 48 of each
// 192-chunk, 4 m-tiles. 1 barrier; W B-frags global->reg per K-half.
// ---------------------------------------------------------------------------
__global__ __launch_bounds__(256, 4) void qkv_kernel(
    const float* __restrict__ X, const unsigned short* __restrict__ Wt,
    const float* __restrict__ b_qkv,
    unsigned short* __restrict__ Qw, unsigned short* __restrict__ Kw,
    unsigned short* __restrict__ Vw) {
    __shared__ unsigned short lx[64 * LXP];
    const int tid = threadIdx.x, bwin = blockIdx.x;
    const int wave = tid >> 6, lane = tid & 63;
    const int l15 = lane & 15, quad = lane >> 4;

    // stage X (fp32 -> bf16), once per window
    const float4* xg = (const float4*)(X + (size_t)bwin * NTOK * WDIM);
    #pragma unroll
    for (int i = 0; i < 12; i++) {
        int e4 = tid + i * 256;                  // 3072 float4
        int row = e4 / 48, c4 = e4 % 48;
        float4 v = xg[e4];
        union { unsigned short s[4]; uint2 u; } pk;
        pk.s[0] = f2bf(v.x); pk.s[1] = f2bf(v.y);
        pk.s[2] = f2bf(v.z); pk.s[3] = f2bf(v.w);
        *(uint2*)&lx[row * LXP + c4 * 4] = pk.u;
    }
    __syncthreads();

    const int nbase = wave * 48;
    #pragma unroll
    for (int chunk = 0; chunk < 3; chunk++) {
        f32x4 acc[4][3];
        #pragma unroll
        for (int mt = 0; mt < 4; mt++)
            #pragma unroll
            for (int nt = 0; nt < 3; nt++)
                acc[mt][nt] = (f32x4){0.f, 0.f, 0.f, 0.f};

        #pragma unroll
        for (int kh = 0; kh < 2; kh++) {
            bf16x8 bfr[3][3];
            #pragma unroll
            for (int nt = 0; nt < 3; nt++)
                #pragma unroll
                for (int k3 = 0; k3 < 3; k3++)
                    bfr[nt][k3] = *(const bf16x8*)&Wt[
                        ((size_t)chunk * 192 + nbase + nt * 16 + l15) * 192 +
                        (kh * 3 + k3) * 32 + quad * 8];
            #pragma unroll
            for (int k3 = 0; k3 < 3; k3++) {
                bf16x8 af[4];
                #pragma unroll
                for (int mt = 0; mt < 4; mt++)
                    af[mt] = *(const bf16x8*)&lx[
                        (mt * 16 + l15) * LXP + (kh * 3 + k3) * 32 + quad * 8];
                #pragma unroll
                for (int mt = 0; mt < 4; mt++)
                    #pragma unroll
                    for (int nt = 0; nt < 3; nt++)
                        acc[mt][nt] = __builtin_amdgcn_mfma_f32_16x16x32_bf16(
                            af[mt], bfr[nt][k3], acc[mt][nt], 0, 0, 0);
            }
        }

        // epilogue: C/D col=l15, row=quad*4+r. Q pre-scaled.
        unsigned short* dst = (chunk == 0) ? Qw : (chunk == 1) ? Kw : Vw;
        const float scl = (chunk == 0) ? SCALE : 1.0f;
        #pragma unroll
        for (int nt = 0; nt < 3; nt++) {
            int cw = nbase + nt * 16 + l15;          // 0..191
            float bias = b_qkv[chunk * 192 + cw];
            int h = cw >> 5, d = cw & 31;
            size_t base = ((size_t)(bwin * NH + h)) * NTOK * HD + d;
            #pragma unroll
            for (int mt = 0; mt < 4; mt++)
                #pragma unroll
                for (int r = 0; r < 4; r++) {
                    int t = mt * 16 + quad * 4 + r;
                    dst[base + (size_t)t * HD] = f2bf((acc[mt][nt][r] + bias) * scl);
                }
        }
    }
}

// ---------------------------------------------------------------------------
// K2: attention. Block = (window, head). comb read direct from global.
// V^T staging uses rotated write order: bank base 36*(d+jj) mod 32 becomes
// {4j,4j+4,4j+8,4j+12} across the 4 d-groups -> no 8-way conflicts.
// ---------------------------------------------------------------------------
__global__ __launch_bounds__(256, 4) void attn_kernel(
    const unsigned short* __restrict__ Qw, const unsigned short* __restrict__ Kw,
    const unsigned short* __restrict__ Vw, const float* __restrict__ comb,
    unsigned short* __restrict__ xatt) {
    __shared__ unsigned short lq[64 * LQP];      // 5.1 KB
    __shared__ unsigned short lk[64 * LQP];      // 5.1 KB
    __shared__ unsigned short lvt[32 * LVP];     // 4.6 KB
    __shared__ unsigned short lp[4 * 16 * LPP];  // 9.2 KB per-wave P

    const int tid = threadIdx.x;
    const int bwh = blockIdx.x;
    const int bwin = bwh / NH, h = bwh % NH;

    // stage Q, K, V^T
    {
        int e = tid * 8;                   // 2048 bf16 each
        int t = e >> 5, d = e & 31;
        const unsigned short* qg = Qw + (size_t)bwh * 2048;
        const unsigned short* kg = Kw + (size_t)bwh * 2048;
        const unsigned short* vg = Vw + (size_t)bwh * 2048;
        *(uint4*)&lq[t * LQP + d] = *(const uint4*)&qg[e];
        *(uint4*)&lk[t * LQP + d] = *(const uint4*)&kg[e];
        union { uint4 u; unsigned short s[8]; } vv;
        vv.u = *(const uint4*)&vg[e];
        #pragma unroll
        for (int j = 0; j < 8; j++) {
            int jj = (j + (d >> 3)) & 7;         // rotation kills bank collision
            lvt[(d + jj) * LVP + t] = vv.s[jj];
        }
    }
    __syncthreads();

    const int wave = tid >> 6, lane = tid & 63;
    const int l15 = lane & 15, quad = lane >> 4;
    const int mbase = wave * 16;
    const float* cb = comb + ((size_t)(bwin & 63) * NH + h) * 4096;
    unsigned short* pw = &lp[wave * 16 * LPP];

    // S = Q K^T (Q pre-scaled)
    bf16x8 aq = *(const bf16x8*)&lq[(mbase + l15) * LQP + quad * 8];
    f32x4 sacc[4];
    #pragma unroll
    for (int j = 0; j < 4; j++) {
        bf16x8 bk = *(const bf16x8*)&lk[(j * 16 + l15) * LQP + quad * 8];
        f32x4 z = (f32x4){0.f, 0.f, 0.f, 0.f};
        sacc[j] = __builtin_amdgcn_mfma_f32_16x16x32_bf16(aq, bk, z, 0, 0, 0);
    }

    // softmax fp32: row = mbase+quad*4+r in 16-lane shfl group
    float s[4][4];
    #pragma unroll
    for (int j = 0; j < 4; j++)
        #pragma unroll
        for (int r = 0; r < 4; r++)
            s[j][r] = sacc[j][r] + cb[(mbase + quad * 4 + r) * 64 + j * 16 + l15];
    float p[4][4], rsum[4];
    #pragma unroll
    for (int r = 0; r < 4; r++) {
        float m = fmaxf(fmaxf(s[0][r], s[1][r]), fmaxf(s[2][r], s[3][r]));
        for (int o = 1; o < 16; o <<= 1) m = fmaxf(m, __shfl_xor(m, o, 64));
        #pragma unroll
        for (int j = 0; j < 4; j++) p[j][r] = __expf(s[j][r] - m);
        float su = p[0][r] + p[1][r] + p[2][r] + p[3][r];
        for (int o = 1; o < 16; o <<= 1) su += __shfl_xor(su, o, 64);
        rsum[r] = su;
    }
    #pragma unroll
    for (int j = 0; j < 4; j++)
        #pragma unroll
        for (int r = 0; r < 4; r++)
            pw[(quad * 4 + r) * LPP + j * 16 + l15] = f2bf(p[j][r]);

    // O = P V
    f32x4 oacc[2];
    oacc[0] = (f32x4){0.f, 0.f, 0.f, 0.f};
    oacc[1] = (f32x4){0.f, 0.f, 0.f, 0.f};
    #pragma unroll
    for (int kstep = 0; kstep < 2; kstep++) {
        bf16x8 ap = *(const bf16x8*)&pw[l15 * LPP + kstep * 32 + quad * 8];
        #pragma unroll
        for (int n2 = 0; n2 < 2; n2++) {
            bf16x8 bv = *(const bf16x8*)&lvt[
                (n2 * 16 + l15) * LVP + kstep * 32 + quad * 8];
            oacc[n2] = __builtin_amdgcn_mfma_f32_16x16x32_bf16(ap, bv, oacc[n2], 0, 0, 0);
        }
    }
    unsigned short* og = xatt + (size_t)bwin * NTOK * WDIM + h * HD;
    #pragma unroll
    for (int r = 0; r < 4; r++) {
        float inv = 1.0f / rsum[r];
        int t = mbase + quad * 4 + r;
        #pragma unroll
        for (int n2 = 0; n2 < 2; n2++)
            og[(size_t)t * WDIM + n2 * 16 + l15] = f2bf(oacc[n2][r] * inv);
    }
}

// ---------------------------------------------------------------------------
// K3: output projection. Block = window, 1 barrier, W B-frags in regs.
// ---------------------------------------------------------------------------
__global__ __launch_bounds__(256, 4) void proj_kernel(
    const unsigned short* __restrict__ Xa, const unsigned short* __restrict__ Wt,
    const float* __restrict__ b_proj, float* __restrict__ out) {
    __shared__ unsigned short lx[64 * LXP];
    const int tid = threadIdx.x;
    const int bwin = blockIdx.x;

    const unsigned short* xg = Xa + (size_t)bwin * NTOK * WDIM;
    #pragma unroll
    for (int i = 0; i < 6; i++) {
        int e8 = tid + i * 256;                  // 1536 chunks of 8 bf16
        int row = e8 / 24, c8 = e8 % 24;
        *(uint4*)&lx[row * LXP + c8 * 8] = *(const uint4*)&xg[row * 192 + c8 * 8];
    }
    __syncthreads();

    const int wave = tid >> 6, lane = tid & 63;
    const int l15 = lane & 15, quad = lane >> 4;
    const int nbase = wave * 48;

    f32x4 acc[4][3];
    #pragma unroll
    for (int mt = 0; mt < 4; mt++)
        #pragma unroll
        for (int nt = 0; nt < 3; nt++)
            acc[mt][nt] = (f32x4){0.f, 0.f, 0.f, 0.f};

    #pragma unroll
    for (int kh = 0; kh < 2; kh++) {
        bf16x8 pfr[3][3];
        #pragma unroll
        for (int nt = 0; nt < 3; nt++)
            #pragma unroll
            for (int k3 = 0; k3 < 3; k3++)
                pfr[nt][k3] = *(const bf16x8*)&Wt[
                    (size_t)(nbase + nt * 16 + l15) * 192 + (kh * 3 + k3) * 32 + quad * 8];
        #pragma unroll
        for (int k3 = 0; k3 < 3; k3++) {
            bf16x8 af[4];
            #pragma unroll
            for (int mt = 0; mt < 4; mt++)
                af[mt] = *(const bf16x8*)&lx[
                    (mt * 16 + l15) * LXP + (kh * 3 + k3) * 32 + quad * 8];
            #pragma unroll
            for (int mt = 0; mt < 4; mt++)
                #pragma unroll
                for (int nt = 0; nt < 3; nt++)
                    acc[mt][nt] = __builtin_amdgcn_mfma_f32_16x16x32_bf16(
                        af[mt], pfr[nt][k3], acc[mt][nt], 0, 0, 0);
        }
    }

    #pragma unroll
    for (int nt = 0; nt < 3; nt++) {
        int cw = nbase + nt * 16 + l15;
        float bias = b_proj[cw];
        #pragma unroll
        for (int mt = 0; mt < 4; mt++)
            #pragma unroll
            for (int r = 0; r < 4; r++) {
                int t = mt * 16 + quad * 4 + r;
                out[((size_t)bwin * NTOK + t) * WDIM + cw] = acc[mt][nt][r] + bias;
            }
    }
}

// ---------------------------------------------------------------------------
extern "C" void kernel_launch(void* const* d_in, const int* in_sizes, int n_in,
                              void* d_out, int out_size, void* d_ws, size_t ws_size,
                              hipStream_t stream) {
    const float* x      = (const float*)d_in[0];
    const float* mask   = (const float*)d_in[1];
    const float* w_qkv  = (const float*)d_in[2];
    const float* b_qkv  = (const float*)d_in[3];
    const float* rpbt   = (const float*)d_in[4];
    const float* w_proj = (const float*)d_in[5];
    const float* b_proj = (const float*)d_in[6];
    float* out = (float*)d_out;

    const int B = in_sizes[0] / (NTOK * WDIM);   // 2048

    char* ws = (char*)d_ws;
    size_t o = 0;
    unsigned short* Wq = (unsigned short*)(ws + o); o += 576 * 192 * 2;
    unsigned short* Wp = (unsigned short*)(ws + o); o += 192 * 192 * 2;
    float* comb        = (float*)(ws + o);         o += (size_t)64 * NH * NTOK * NTOK * 4;
    unsigned short* Qw = (unsigned short*)(ws + o); o += (size_t)B * NH * NTOK * HD * 2;
    unsigned short* Kw = (unsigned short*)(ws + o); o += (size_t)B * NH * NTOK * HD * 2;
    unsigned short* Vw = (unsigned short*)(ws + o); o += (size_t)B * NH * NTOK * HD * 2;
    unsigned short* Xa = (unsigned short*)(ws + o); o += (size_t)B * NTOK * WDIM * 2;

    const int prep_elems = 576 * 192 + 192 * 192 + 64 * NH * NTOK * NTOK;
    prep_kernel<<<(prep_elems + 255) / 256, 256, 0, stream>>>(
        w_qkv, w_proj, rpbt, mask, Wq, Wp, comb);
    qkv_kernel<<<B, 256, 0, stream>>>(x, Wq, b_qkv, Qw, Kw, Vw);
    attn_kernel<<<B * NH, 256, 0, stream>>>(Qw, Kw, Vw, comb, Xa);
    proj_kernel<<<B, 256, 0, stream>>>(Xa, Wp, b_proj, out);
}